// Round 1
// baseline (533.999 us; speedup 1.0000x reference)
//
#include <hip/hip_runtime.h>
#include <hip/hip_bf16.h>

typedef _Float16 half8 __attribute__((ext_vector_type(8)));
typedef float floatx4 __attribute__((ext_vector_type(4)));

// ---------------------------------------------------------------------------
// Kernel 1: Sinkhorn on the 128x128 matrix, factored form.
// One block, 128 threads. Thread i owns row i of A0 (regs) and column i of A0
// (regs, via one LDS transpose). A0 is never rescaled; instead we iterate
//   r = 1 / (A0 c)        (row-normalize step)
//   c = 1 / (A0^T r)      (col-normalize step)
// Final P[i][j] = r_i * A0[i][j] * c_j, written row-major as f16 into d_ws.
// ---------------------------------------------------------------------------
__global__ __launch_bounds__(128, 1) void sinkhorn128(
    const float* __restrict__ logits, const float* __restrict__ u,
    _Float16* __restrict__ Pout) {
    __shared__ float sA[128 * 129];           // +1 pad: conflict-free transpose
    __shared__ alignas(16) float sVec[128];   // broadcast vector (c or r)
    const int i = threadIdx.x;

    float a0[128];   // row i of A0
    float a0t[128];  // column i of A0

    // A0 = exp(clip((logits + gumbel)/T, -10, 10))
    #pragma unroll
    for (int j = 0; j < 128; ++j) {
        float lg = logits[i * 128 + j];
        float uu = u[i * 128 + j];
        float g  = -logf(-logf(uu + 1e-20f) + 1e-20f);  // NOISE_SCALE = 1
        float la = (lg + g) / 3.0f;                      // TEMPERATURE = 3
        la = fminf(10.0f, fmaxf(-10.0f, la));
        float a = expf(la);
        a0[j] = a;
        sA[i * 129 + j] = a;
    }
    sVec[i] = 1.0f;  // c := ones
    __syncthreads();
    #pragma unroll
    for (int j = 0; j < 128; ++j) a0t[j] = sA[j * 129 + i];  // transpose read

    float ri = 1.0f;
    for (int it = 0; it < 20; ++it) {
        // row phase: ri = 1 / sum_j a0[j] * c[j]
        float s0 = 0.f, s1 = 0.f, s2 = 0.f, s3 = 0.f;
        #pragma unroll
        for (int j = 0; j < 128; j += 4) {
            float4 c4 = *reinterpret_cast<const float4*>(&sVec[j]);
            s0 = fmaf(a0[j + 0], c4.x, s0);
            s1 = fmaf(a0[j + 1], c4.y, s1);
            s2 = fmaf(a0[j + 2], c4.z, s2);
            s3 = fmaf(a0[j + 3], c4.w, s3);
        }
        ri = 1.0f / ((s0 + s1) + (s2 + s3));
        __syncthreads();          // everyone done reading c
        sVec[i] = ri;
        __syncthreads();          // r visible
        // col phase: ci = 1 / sum_j a0t[j] * r[j]
        s0 = s1 = s2 = s3 = 0.f;
        #pragma unroll
        for (int j = 0; j < 128; j += 4) {
            float4 r4 = *reinterpret_cast<const float4*>(&sVec[j]);
            s0 = fmaf(a0t[j + 0], r4.x, s0);
            s1 = fmaf(a0t[j + 1], r4.y, s1);
            s2 = fmaf(a0t[j + 2], r4.z, s2);
            s3 = fmaf(a0t[j + 3], r4.w, s3);
        }
        float ci = 1.0f / ((s0 + s1) + (s2 + s3));
        __syncthreads();          // everyone done reading r
        sVec[i] = ci;
        __syncthreads();          // c visible
    }

    // P row i = ri * a0[j] * c[j], cast to f16, row-major (this IS B^T's row n)
    #pragma unroll
    for (int j = 0; j < 128; j += 2) {
        union { _Float16 h[2]; unsigned int w; } pk;
        pk.h[0] = (_Float16)(ri * a0[j + 0] * sVec[j + 0]);
        pk.h[1] = (_Float16)(ri * a0[j + 1] * sVec[j + 1]);
        reinterpret_cast<unsigned int*>(Pout)[(i * 128 + j) >> 1] = pk.w;
    }
}

// ---------------------------------------------------------------------------
// Kernel 2: out = x @ P.T, streaming MFMA, no LDS.
// Each wave keeps ALL B fragments (P.T, f16) in 128 VGPRs and processes 16
// blocks of 16 rows. x is split into f16 hi + f16 lo (2 MFMAs/accumulate) so
// the f32->f16 input rounding error is ~2^-22 on the x side.
// A-frag: lane holds x[m0 + (l&15)][ks*32 + (l>>4)*8 + j]  (8 contiguous f32)
// B-frag: lane holds P[nt*16 + (l&15)][ks*32 + (l>>4)*8 + j] (8 contiguous f16)
// C/D:    lane l holds C[(l>>4)*4 + rr][l&15]
// ---------------------------------------------------------------------------
__global__ __launch_bounds__(256, 2) void streamMatmul(
    const float* __restrict__ x, const _Float16* __restrict__ P,
    float* __restrict__ out) {
    const int lane = threadIdx.x & 63;
    const int wv   = threadIdx.x >> 6;
    const int gw   = blockIdx.x * 4 + wv;   // 0..2047
    const int r    = lane & 15;
    const int q    = lane >> 4;

    // Load all B fragments once: 4 k-steps x 8 n-tiles x 8 f16 = 128 VGPRs
    half8 Bf[4][8];
    #pragma unroll
    for (int ks = 0; ks < 4; ++ks)
        #pragma unroll
        for (int nt = 0; nt < 8; ++nt)
            Bf[ks][nt] = *reinterpret_cast<const half8*>(
                P + (nt * 16 + r) * 128 + ks * 32 + q * 8);

    const long baseRow = (long)gw * 256;    // 2048 waves x 256 rows = 524288
    for (int t = 0; t < 16; ++t) {
        const long m0 = baseRow + t * 16;
        const float* xp = x + (m0 + r) * 128 + q * 8;

        // Issue all x loads (8 x dwordx4, nontemporal) before converting
        floatx4 xa[4][2];
        #pragma unroll
        for (int ks = 0; ks < 4; ++ks) {
            xa[ks][0] = __builtin_nontemporal_load(
                reinterpret_cast<const floatx4*>(xp + ks * 32));
            xa[ks][1] = __builtin_nontemporal_load(
                reinterpret_cast<const floatx4*>(xp + ks * 32 + 4));
        }

        floatx4 acc[8];
        #pragma unroll
        for (int nt = 0; nt < 8; ++nt) acc[nt] = (floatx4){0.f, 0.f, 0.f, 0.f};

        #pragma unroll
        for (int ks = 0; ks < 4; ++ks) {
            half8 ahi, alo;
            #pragma unroll
            for (int jj = 0; jj < 8; ++jj) {
                float f = (jj < 4) ? xa[ks][0][jj] : xa[ks][1][jj - 4];
                _Float16 h = (_Float16)f;
                ahi[jj] = h;
                alo[jj] = (_Float16)(f - (float)h);
            }
            #pragma unroll
            for (int nt = 0; nt < 8; ++nt) {
                acc[nt] = __builtin_amdgcn_mfma_f32_16x16x32_f16(
                    ahi, Bf[ks][nt], acc[nt], 0, 0, 0);
                acc[nt] = __builtin_amdgcn_mfma_f32_16x16x32_f16(
                    alo, Bf[ks][nt], acc[nt], 0, 0, 0);
            }
        }

        // Store: lane l owns rows (q*4 + rr), col (nt*16 + r).
        // 16 lanes x 4B = 64B contiguous per row per instr -> coalesced 64B segs.
        float* op = out + (m0 + q * 4) * 128 + r;
        #pragma unroll
        for (int nt = 0; nt < 8; ++nt)
            #pragma unroll
            for (int rr = 0; rr < 4; ++rr)
                __builtin_nontemporal_store(acc[nt][rr], op + rr * 128 + nt * 16);
    }
}

extern "C" void kernel_launch(void* const* d_in, const int* in_sizes, int n_in,
                              void* d_out, int out_size, void* d_ws, size_t ws_size,
                              hipStream_t stream) {
    (void)in_sizes; (void)n_in; (void)out_size; (void)ws_size;
    const float* x      = (const float*)d_in[0];  // [524288,128] f32
    const float* logits = (const float*)d_in[1];  // [128,128] f32
    const float* u      = (const float*)d_in[2];  // [128,128] f32
    float* out          = (float*)d_out;          // [524288,128] f32
    _Float16* P         = (_Float16*)d_ws;        // [128,128] f16 scratch

    sinkhorn128<<<1, 128, 0, stream>>>(logits, u, P);
    streamMatmul<<<512, 256, 0, stream>>>(x, P, out);
}